// Round 12
// baseline (377.962 us; speedup 1.0000x reference)
//
#include <hip/hip_runtime.h>
#include <hip/hip_bf16.h>
#include <math.h>

// MultiHeadCA bf16-MFMA pipeline. Transposed flash attention (this round:
// QB=128, 1 q-set/wave, 8 waves -> 4 blocks/CU, 32 waves/CU), K-row
// permutation (lane-local P frags), native v_exp_f32 softmax, ones-MFMA
// row-sums, mask packed to C-frag order by LDS-coalesced mask_prep (this
// round: staged 16x512 slab, coalesced reads). KV+Q GEMM: 256x256 4-phase
// counted-vmcnt pipeline. Out-proj: m97 2-buffer. XCD swizzle on GEMMs.
// B=4, T=2048, D=1024, NH=16, HEAD=64.

#define D_MODEL 1024
#define NH      16
#define HEAD    64
#define BATCH   4
#define SEQ     2048
#define QB      128

#define LOG2E   1.44269504088896f

typedef unsigned int   u32;
typedef unsigned short u16;
typedef __attribute__((ext_vector_type(8))) short s16x8;   // 8 bf16 (4 VGPRs)
typedef __attribute__((ext_vector_type(4))) float f32x4;   // MFMA C/D
typedef __attribute__((ext_vector_type(4))) unsigned int u32v4;

__device__ __forceinline__ u16 tobf(float f) {   // RNE f32->bf16
    u32 u = __builtin_bit_cast(u32, f);
    return (u16)((u + 0x7fffu + ((u >> 16) & 1u)) >> 16);
}
__device__ __forceinline__ float frombf(u16 u) {
    return __builtin_bit_cast(float, (u32)u << 16);
}
// HW packed f32->bf16 (RNE): dst.lo = bf16(a), dst.hi = bf16(b)
__device__ __forceinline__ u32 cvtpk(float a, float b) {
    u32 r;
    asm("v_cvt_pk_bf16_f32 %0, %1, %2" : "=v"(r) : "v"(a), "v"(b));
    return r;
}
// native 2^x (exp2f is OCML's slow precise path; v_exp_f32 IS exp2)
__device__ __forceinline__ float fexp2(float x) {
    float r;
    asm("v_exp_f32 %0, %1" : "=v"(r) : "v"(x));
    return r;
}

__device__ __forceinline__ void gl_lds16(const void* g, void* l) {
    __builtin_amdgcn_global_load_lds(
        (const __attribute__((address_space(1))) u32*)g,
        (__attribute__((address_space(3))) u32*)l, 16, 0, 0);
}

// ---------------- merged prep: casts (blocks 0..16383) + W^T (16384..20479) -
__global__ __launch_bounds__(256) void prep_all(
    const float* __restrict__ x_enc, const float* __restrict__ x_dec,
    u16* __restrict__ xout, int n,
    const float* __restrict__ Wq,  u16* __restrict__ wqT,
    const float* __restrict__ Wkv, u16* __restrict__ wkvT,
    const float* __restrict__ Wo,  u16* __restrict__ woT)
{
    __shared__ __align__(16) float tile[32][33];
    const int bid = blockIdx.x;
    if (bid < 16384) {
        const int y  = bid >> 13;           // 0: enc, 1: dec
        const int bx = bid & 8191;
        const float* in = y ? x_dec : x_enc;
        u16* o = xout + (size_t)y * n;
        int i = (bx * 256 + threadIdx.x) * 4;
        if (i < n) {
            float4 v = *(const float4*)(in + i);
            ushort4 ov = make_ushort4(tobf(v.x), tobf(v.y), tobf(v.z), tobf(v.w));
            *(ushort4*)(o + i) = ov;
        }
        return;
    }
    const int tb = bid - 16384;             // 0..4095
    const int z  = tb >> 10;                // 0..3
    const int rb = tb & 1023;
    const int bxT = rb & 31, byT = rb >> 5;
    const int K = D_MODEL;
    const float* W = (z == 0) ? Wq : (z == 3) ? Wo : Wkv;
    u16* WT       = (z == 0) ? wqT : (z == 3) ? woT : wkvT;
    const int N   = (z == 1 || z == 2) ? 2*D_MODEL : D_MODEL;
    const int nb  = (z == 2) ? D_MODEL : 0;
    const int n0 = nb + bxT * 32, k0 = byT * 32;
    const int r = threadIdx.x >> 3, c4 = (threadIdx.x & 7) * 4;
    float4 v = *(const float4*)&W[(size_t)(k0 + r) * N + n0 + c4];
    tile[r][c4] = v.x; tile[r][c4+1] = v.y; tile[r][c4+2] = v.z; tile[r][c4+3] = v.w;
    __syncthreads();
    ushort4 o = make_ushort4(tobf(tile[c4+0][r]), tobf(tile[c4+1][r]),
                             tobf(tile[c4+2][r]), tobf(tile[c4+3][r]));
    *(ushort4*)&WT[(size_t)(n0 + r) * K + k0 + c4] = o;
}

// ---------------- mask f32 -> bf16 C-frag tiles, LDS-coalesced -------------
// Block (qt, kseg, b): stage mask[b][qt*16..+16)[kseg*512..+512) as bf16*LOG2E
// into LDS with fully-coalesced float4 reads (8/thread), then emit the 32
// permuted 16x16 tiles: tile kt'=kseg*32+i, lane l writes the contiguous 8B
// mp[tile*256 + l*4] = ms[l&15][klocal(kt',quad)+0..3]. Output bit-identical
// to the previous scattered-read version.
__global__ __launch_bounds__(256) void mask_prep(
    const float* __restrict__ mask, u16* __restrict__ mp)
{
    __shared__ __align__(16) u16 ms[16][520];
    const int t = threadIdx.x;
    const int w = t >> 6, l = t & 63;
    const int qt = blockIdx.x, kseg = blockIdx.y, b = blockIdx.z;
    const float* src = mask + ((size_t)(b*SEQ + qt*16))*SEQ + kseg*512;
    #pragma unroll
    for (int p = 0; p < 8; ++p) {
        const int idx = p*256 + t;        // 0..2047 = 16 rows x 128 float4
        const int row = idx >> 7, c4 = (idx & 127) * 4;
        float4 v = *(const float4*)(src + (size_t)row*SEQ + c4);
        ushort4 o = make_ushort4(tobf(v.x*LOG2E), tobf(v.y*LOG2E),
                                 tobf(v.z*LOG2E), tobf(v.w*LOG2E));
        *(ushort4*)&ms[row][c4] = o;
    }
    __syncthreads();
    const int q15 = l & 15, quad = l >> 4;
    u16* dst = mp + (((size_t)b*128 + qt)*128 + (size_t)kseg*32)*256 + (size_t)l*4;
    #pragma unroll
    for (int i = 0; i < 8; ++i) {
        const int ktp = w*8 + i;           // 0..31 within this 512-k segment
        const int klocal = (ktp>>2)*64 + ((ktp>>1)&1)*32 + (ktp&1)*4 + quad*8;
        *(uint2*)(dst + (size_t)ktp*256) = *(const uint2*)&ms[q15][klocal];
    }
}

// XCD-aware bijective block swizzle (requires nwg % 8 == 0).
__device__ __forceinline__ void xcd_swz(int& bx, int& by) {
    const int gx = gridDim.x;
    const int nwg = gx * gridDim.y;
    const int orig = by * gx + bx;
    const int swz = (orig & 7) * (nwg >> 3) + (orig >> 3);
    bx = swz % gx; by = swz / gx;
}

// ---------------- m97-style GEMM + single-barrier double-buffer (out-proj) --
__device__ __forceinline__ void store_out(u16* p, float v)  { *p = tobf(v); }
__device__ __forceinline__ void store_out(float* p, float v){ *p = v; }

template <typename OT>
__global__ __launch_bounds__(256) void gemm_bt(
    const u16* __restrict__ A, const u16* __restrict__ Bt,
    const float* __restrict__ bias, OT* __restrict__ C,
    int N, int K, float out_scale)
{
    __shared__ __align__(16) u16 As[2][128 * 32];
    __shared__ __align__(16) u16 Bs[2][128 * 32];
    const int t = threadIdx.x;
    const int w = t >> 6, l = t & 63;
    const int lane15 = l & 15, quad = l >> 4;
    int bx = blockIdx.x, by = blockIdx.y;
    xcd_swz(bx, by);
    const int m0 = by * 128, n0 = bx * 128;
    const int wm = (w >> 1) * 64, wn = (w & 1) * 64;
    const int lr = l >> 2, lk = (l & 3) * 8;

    auto stage = [&](int k0, int bufi) {
        #pragma unroll
        for (int i = 0; i < 2; ++i) {
            const int chunk = w * 2 + i;
            gl_lds16(A  + (size_t)(m0 + chunk*16 + lr) * K + k0 + lk,
                     &As[bufi][chunk * 512]);
            gl_lds16(Bt + (size_t)(n0 + chunk*16 + lr) * K + k0 + lk,
                     &Bs[bufi][chunk * 512]);
        }
    };

    f32x4 acc[4][4] = {};
    const int nb = K >> 5;
    stage(0, 0);

    for (int i = 0; i < nb; ++i) {
        const int cur = i & 1;
        __syncthreads();
        if (i + 1 < nb) stage((i + 1) << 5, cur ^ 1);
        s16x8 af[4], bfr[4];
        #pragma unroll
        for (int i2 = 0; i2 < 4; ++i2)
            af[i2] = *(const s16x8*)&As[cur][(wm + i2*16 + lane15) * 32 + quad * 8];
        #pragma unroll
        for (int j = 0; j < 4; ++j)
            bfr[j] = *(const s16x8*)&Bs[cur][(wn + j*16 + lane15) * 32 + quad * 8];
        #pragma unroll
        for (int i2 = 0; i2 < 4; ++i2)
            #pragma unroll
            for (int j = 0; j < 4; ++j)
                acc[i2][j] = __builtin_amdgcn_mfma_f32_16x16x32_bf16(
                    af[i2], bfr[j], acc[i2][j], 0, 0, 0);
    }
    #pragma unroll
    for (int j = 0; j < 4; ++j) {
        const int col = n0 + wn + j*16 + lane15;
        const float bv = bias[col];
        #pragma unroll
        for (int i = 0; i < 4; ++i)
            #pragma unroll
            for (int r = 0; r < 4; ++r) {
                const int row = m0 + wm + i*16 + quad*4 + r;
                store_out(C + (size_t)row * N + col, (acc[i][j][r] + bv) * out_scale);
            }
    }
}

// ---------------- KV+Q GEMM: 256x256 tile, BK=64, 4-phase deep pipeline ----
// (unchanged from round 11; verified)
__global__ __launch_bounds__(512, 1) void gemm_kvq256(
    const u16* __restrict__ xe, const u16* __restrict__ xd,
    const u16* __restrict__ wkvT, const u16* __restrict__ wqT,
    const float* __restrict__ bkv, const float* __restrict__ bq,
    u16* __restrict__ kvb, u16* __restrict__ vtb, u16* __restrict__ qbuf)
{
    const int K = D_MODEL;
    const int NT = K / 64;                 // 16 K-tiles
    __shared__ __align__(16) u16 sm[65536];   // 128 KiB
    u16* const smA = sm;
    u16* const smB = sm + 32768;
    const int t = threadIdx.x;
    const int w = t >> 6, l = t & 63;
    const int lane15 = l & 15, quad = l >> 4;
    int bx = blockIdx.x, by = blockIdx.y;
    xcd_swz(bx, by);                       // nwg = 384, %8 == 0
    const bool isq = bx >= 8;
    const u16* A  = isq ? xd : xe;
    const u16* Bt = isq ? wqT : wkvT;
    const int n0 = (isq ? bx - 8 : bx) * 256;
    const int m0 = by * 256;
    const int wm = (w >> 2) * 128;         // 2 M-halves
    const int wn = (w & 3) * 64;           // 4 N-quarters
    const int lr = l >> 2;
    const int lc8 = (((l & 3) ^ (lr & 3)) * 8);   // swizzled source col chunk
    const int cq  = (quad ^ (lane15 & 3)) * 8;    // swizzled frag-read chunk

    auto stageA = [&](int tt, int s) {
        const int base = ((tt & 1) * 2 + s) * 256;
        const int k0 = tt * 64 + s * 32;
        #pragma unroll
        for (int jj = 0; jj < 2; ++jj) {
            const int r0 = jj * 128 + w * 16;
            gl_lds16(A + (size_t)(m0 + r0 + lr) * K + k0 + lc8,
                     smA + (base + r0) * 32);
        }
    };
    auto stageB = [&](int tt, int s) {
        const int base = ((tt & 1) * 2 + s) * 256;
        const int k0 = tt * 64 + s * 32;
        #pragma unroll
        for (int jj = 0; jj < 2; ++jj) {
            const int r0 = jj * 128 + w * 16;
            gl_lds16(Bt + (size_t)(n0 + r0 + lr) * K + k0 + lc8,
                     smB + (base + r0) * 32);
        }
    };

    f32x4 acc[8][4] = {};

    stageB(0,0); stageA(0,0); stageB(0,1); stageA(0,1);
    stageB(1,0); stageA(1,0); stageB(1,1);
    asm volatile("s_waitcnt vmcnt(6)" ::: "memory");
    __builtin_amdgcn_sched_barrier(0);
    __builtin_amdgcn_s_barrier();

    for (int tt = 0; tt < NT; ++tt) {
        const int p = tt & 1;
        const u16* Ab = smA + p * 16384;
        const u16* Bb = smB + p * 16384;
        s16x8 af[4], bfr[4];
        #pragma unroll
        for (int ph = 0; ph < 4; ++ph) {
            const int s = ph >> 1;          // ksub
            const int ih = (ph & 1) * 4;    // acc row-frag offset
            #pragma unroll
            for (int i = 0; i < 4; ++i)
                af[i] = *(const s16x8*)(Ab + s*8192 + (wm + (ih + i)*16 + lane15)*32 + cq);
            if ((ph & 1) == 0) {
                #pragma unroll
                for (int j = 0; j < 4; ++j)
                    bfr[j] = *(const s16x8*)(Bb + s*8192 + (wn + j*16 + lane15)*32 + cq);
            }
            if (ph == 0)      { if (tt + 1 < NT) stageA(tt + 1, 1); }
            else if (ph == 1) { if (tt + 2 < NT) stageB(tt + 2, 0); }
            else if (ph == 2) { if (tt + 2 < NT) stageA(tt + 2, 0); }
            else              { if (tt + 2 < NT) stageB(tt + 2, 1); }
            __builtin_amdgcn_sched_barrier(0);
            __builtin_amdgcn_s_barrier();
            asm volatile("s_waitcnt lgkmcnt(0)" ::: "memory");
            __builtin_amdgcn_sched_barrier(0);
            __builtin_amdgcn_s_setprio(1);
            #pragma unroll
            for (int i = 0; i < 4; ++i)
                #pragma unroll
                for (int j = 0; j < 4; ++j)
                    acc[ih + i][j] = __builtin_amdgcn_mfma_f32_16x16x32_bf16(
                        af[i], bfr[j], acc[ih + i][j], 0, 0, 0);
            __builtin_amdgcn_s_setprio(0);
            __builtin_amdgcn_sched_barrier(0);
            if (ph == 3 && tt + 1 < NT) {
                if (tt + 2 < NT) asm volatile("s_waitcnt vmcnt(6)" ::: "memory");
                else             asm volatile("s_waitcnt vmcnt(0)" ::: "memory");
                __builtin_amdgcn_sched_barrier(0);
            }
            __builtin_amdgcn_s_barrier();
        }
    }

    if (isq) {
        const float sc = 0.125f * LOG2E;   // fold 1/sqrt(HEAD) * log2e
        #pragma unroll
        for (int j = 0; j < 4; ++j) {
            const int col = n0 + wn + j*16 + lane15;
            const float bv = bq[col];
            #pragma unroll
            for (int i = 0; i < 8; ++i)
                #pragma unroll
                for (int r = 0; r < 4; ++r) {
                    const int row = m0 + wm + i*16 + quad*4 + r;
                    qbuf[(size_t)row * D_MODEL + col] = tobf((acc[i][j][r] + bv) * sc);
                }
        }
    } else if ((wn & 64) == 0) {
        #pragma unroll
        for (int j = 0; j < 4; ++j) {
            const int col = n0 + wn + j*16 + lane15;
            const float bv = bkv[col];
            #pragma unroll
            for (int i = 0; i < 8; ++i)
                #pragma unroll
                for (int r = 0; r < 4; ++r) {
                    const int row = m0 + wm + i*16 + quad*4 + r;
                    kvb[(size_t)row * (2*D_MODEL) + col] = tobf(acc[i][j][r] + bv);
                }
        }
    } else {
        const int head = (n0 + wn) >> 7;
        const int bh = (m0 >> 11) * NH + head;
        #pragma unroll
        for (int j = 0; j < 4; ++j) {
            const int d = j*16 + lane15;
            const float bv = bkv[n0 + wn + j*16 + lane15];
            #pragma unroll
            for (int i = 0; i < 8; ++i) {
                const int row = m0 + wm + i*16 + quad*4;
                const int tk = row & (SEQ - 1);
                u16* pp = vtb + ((size_t)bh*64 + d)*SEQ + tk;
                *(uint2*)pp = make_uint2(cvtpk(acc[i][j][0]+bv, acc[i][j][1]+bv),
                                         cvtpk(acc[i][j][2]+bv, acc[i][j][3]+bv));
            }
        }
    }
}

// ---------------- Transposed MFMA flash attention, async dbuf ----------------
// QB=128: 8 waves x 16 q-rows (1 q-set/wave) -> 4 blocks/CU, 32 waves/CU.
// K-tile 64, double-buffered via global_load_lds. K LDS tile rows
// kpos-PERMUTED so each lane's QK^T C-frag values are exactly its PV B-frag
// k-positions -> pf = cvtpk(sv) in-register. Mask as MFMA C-init
// (log2e-scaled, native v_exp_f32 softmax). Row-sums via ones-MFMA.
// No-max softmax (bounded scores). LDS 32 KiB.
__global__ __launch_bounds__(512, 4) void attn_mfma(
    const u16* __restrict__ qb, const u16* __restrict__ kvb,
    const u16* __restrict__ vt, const u16* __restrict__ mp,
    u16* __restrict__ resb)
{
    // sm: Kbuf[2] @0/4096, Vbuf[2] @8192/12288 (u16 units)
    __shared__ __align__(16) u16 sm[4*4096];
    const int t = threadIdx.x;
    const int w = t >> 6, l = t & 63;          // w: 0..7
    const int lane15 = l & 15, quad = l >> 4;
    const int h  = blockIdx.x;
    const int q0 = blockIdx.y * QB;
    const int b  = blockIdx.z;
    const int bh = b * NH + h;
    const int lr4 = l >> 2;                        // LDS row within 16-row tile
    const int lc8 = (((l & 3) ^ (lr4 & 3)) * 8);   // swizzled source col chunk
    const int cq  = (quad ^ (lane15 & 3)) * 8;     // swizzled frag-read chunk
    const int kprow = (lr4 >> 2)*8 + (lr4 & 3);

    // Q fragments: wave w owns q-rows q0 + w*16 + lane15 (Q pre-scaled log2e/8)
    const u16* qrow = qb + (size_t)(b*SEQ + q0 + w*16 + lane15) * D_MODEL + h*HEAD;
    s16x8 aq0 = *(const s16x8*)(qrow + quad*8);
    s16x8 aq1 = *(const s16x8*)(qrow + 32 + quad*8);
    const u16* mrow = mp + (((size_t)b*128 + (q0>>4) + w) * 128) * 256 + (size_t)l*4;

    auto stage = [&](int k0s, int bf) {
        const int hh = w & 1, rr = w >> 1;
        const int krow = (rr >> 1)*32 + (rr & 1)*4 + kprow;
        const u16* kg = kvb + (size_t)(b*SEQ + k0s + krow) * (2*D_MODEL)
                            + h*128 + hh*32 + lc8;
        gl_lds16(kg, sm + bf*4096 + hh*2048 + rr*512);
        const u16* vg = vt + (size_t)(bh*64 + rr*16 + lr4) * SEQ
                           + k0s + hh*32 + lc8;
        gl_lds16(vg, sm + 8192 + bf*4096 + hh*2048 + rr*512);
    };

    f32x4 o_acc[4] = {};
    f32x4 l_acc = {};             // ones-MFMA row-sum accumulator
    ushort4 mreg[4];
    s16x8 vones;
    #pragma unroll
    for (int i = 0; i < 8; ++i) vones[i] = (short)0x3F80;   // bf16 1.0

    stage(0, 0);
    #pragma unroll
    for (int nt = 0; nt < 4; ++nt)
        mreg[nt] = *(const ushort4*)(mrow + (size_t)nt * 256);

    for (int it = 0; it < SEQ/64; ++it) {
        const int k0 = it * 64;
        const int bf = it & 1;
        __syncthreads();   // drains gl_lds + mask loads; syncs prev compute
        if (it + 1 < SEQ/64)
            stage(k0 + 64, bf ^ 1);

        // QK^T: C-init from mask regs (mreg last use)
        f32x4 sv[4];
        #pragma unroll
        for (int nt = 0; nt < 4; ++nt) {
            sv[nt][0] = frombf(mreg[nt].x); sv[nt][1] = frombf(mreg[nt].y);
            sv[nt][2] = frombf(mreg[nt].z); sv[nt][3] = frombf(mreg[nt].w);
        }
        __builtin_amdgcn_s_setprio(1);
        #pragma unroll
        for (int nt = 0; nt < 4; ++nt) {
            s16x8 kf0 = *(const s16x8*)(sm + bf*4096 +        (nt*16 + lane15)*32 + cq);
            s16x8 kf1 = *(const s16x8*)(sm + bf*4096 + 2048 + (nt*16 + lane15)*32 + cq);
            sv[nt] = __builtin_amdgcn_mfma_f32_16x16x32_bf16(kf0, aq0, sv[nt], 0, 0, 0);
            sv[nt] = __builtin_amdgcn_mfma_f32_16x16x32_bf16(kf1, aq1, sv[nt], 0, 0, 0);
        }
        __builtin_amdgcn_s_setprio(0);

        // mask prefetch for next iter (mreg dead after C-init above)
        if (it + 1 < SEQ/64) {
            #pragma unroll
            for (int nt = 0; nt < 4; ++nt)
                mreg[nt] = *(const ushort4*)(mrow + ((size_t)((k0+64)>>4) + nt) * 256);
        }

        // exp2 + pack: lane-local P frags (K-row permutation).
        s16x8 pf[2];
        #pragma unroll
        for (int hf = 0; hf < 2; ++hf) {
            u32v4 pk;
            pk[0] = cvtpk(fexp2(sv[2*hf][0]),   fexp2(sv[2*hf][1]));
            pk[1] = cvtpk(fexp2(sv[2*hf][2]),   fexp2(sv[2*hf][3]));
            pk[2] = cvtpk(fexp2(sv[2*hf+1][0]), fexp2(sv[2*hf+1][1]));
            pk[3] = cvtpk(fexp2(sv[2*hf+1][2]), fexp2(sv[2*hf+1][3]));
            pf[hf] = __builtin_bit_cast(s16x8, pk);
        }

        // PV: O^T += V^T . P^T  (+ row-sum via ones-MFMA)
        __builtin_amdgcn_s_setprio(1);
        l_acc = __builtin_amdgcn_mfma_f32_16x16x32_bf16(vones, pf[0], l_acc, 0, 0, 0);
        l_acc = __builtin_amdgcn_mfma_f32_16x16x32_bf16(vones, pf[1], l_acc, 0, 0, 0);
        #pragma unroll
        for (int dt = 0; dt < 4; ++dt) {
            s16x8 vf0 = *(const s16x8*)(sm + 8192 + bf*4096 +        (dt*16 + lane15)*32 + cq);
            s16x8 vf1 = *(const s16x8*)(sm + 8192 + bf*4096 + 2048 + (dt*16 + lane15)*32 + cq);
            o_acc[dt] = __builtin_amdgcn_mfma_f32_16x16x32_bf16(vf0, pf[0], o_acc[dt], 0, 0, 0);
            o_acc[dt] = __builtin_amdgcn_mfma_f32_16x16x32_bf16(vf1, pf[1], o_acc[dt], 0, 0, 0);
        }
        __builtin_amdgcn_s_setprio(0);
    }

    // Epilogue: O^T (col=q, row=d) -> LDS transpose (stride 64, 16 KiB for
    // 128 rows) -> coalesced store.
    __syncthreads();
    {
        const float inv = 1.f / l_acc[0];
        u16* orow = &sm[(w*16 + lane15) * 64];
        #pragma unroll
        for (int dt = 0; dt < 4; ++dt) {
            *(uint2*)&orow[dt*16 + quad*4] = make_uint2(
                cvtpk(o_acc[dt][0]*inv, o_acc[dt][1]*inv),
                cvtpk(o_acc[dt][2]*inv, o_acc[dt][3]*inv));
        }
    }
    __syncthreads();
    {
        const int tr = t >> 2, tc = (t & 3) * 16;
        u16* o = resb + (size_t)(b*SEQ + q0 + tr) * D_MODEL + h*HEAD + tc;
        *(uint4*)o       = *(const uint4*)&sm[tr*64 + tc];
        *(uint4*)(o + 8) = *(const uint4*)&sm[tr*64 + tc + 8];
    }
}

extern "C" void kernel_launch(void* const* d_in, const int* in_sizes, int n_in,
                              void* d_out, int out_size, void* d_ws, size_t ws_size,
                              hipStream_t stream) {
    const float* x_enc = (const float*)d_in[0];
    const float* x_dec = (const float*)d_in[1];
    const float* mask  = (const float*)d_in[2];
    const float* Wq    = (const float*)d_in[3];
    const float* bq    = (const float*)d_in[4];
    const float* Wkv   = (const float*)d_in[5];
    const float* bkv   = (const float*)d_in[6];
    const float* Wo    = (const float*)d_in[7];
    const float* bo    = (const float*)d_in[8];
    float* out = (float*)d_out;

    const int M = BATCH * SEQ;  // 8192
    u16* xe   = (u16*)d_ws;                       // 8192x1024 (16.8 MB)
    u16* xd   = xe   + (size_t)M * D_MODEL;       // 8192x1024 (16.8 MB)
    u16* wqT  = xd   + (size_t)M * D_MODEL;       // 1024x1024
    u16* wkvT = wqT  + (size_t)D_MODEL * D_MODEL; // 2048x1024
    u16* woT  = wkvT + (size_t)2*D_MODEL*D_MODEL; // 1024x1024
    u16* qbuf = woT  + (size_t)D_MODEL * D_MODEL; // 8192x1024 (holds Q*log2e/8)
    u16* kvb  = qbuf + (size_t)M * D_MODEL;       // 8192x2048 (K-half valid)
    u16* vtb  = kvb  + (size_t)M * 2 * D_MODEL;   // 64x64x2048
    u16* resb = vtb  + (size_t)BATCH*NH*HEAD*SEQ; // 8192x1024
    u16* mpk  = xe;   // mask C-frag buffer (33.6 MB) aliases xe+xd after GEMMs

    const int NX = M * D_MODEL;  // 8388608
    prep_all<<<16384 + 4096, 256, 0, stream>>>(
        x_enc, x_dec, xe, NX, Wq, wqT, Wkv, wkvT, Wo, woT);

    gemm_kvq256<<<dim3(12, 32), 512, 0, stream>>>(
        xe, xd, wkvT, wqT, bkv, bq, kvb, vtb, qbuf);
    // xe/xd dead now; pack mask into their space
    mask_prep<<<dim3(SEQ/16, 4, BATCH), 256, 0, stream>>>(mask, mpk);
    attn_mfma<<<dim3(NH, SEQ/QB, BATCH), 512, 0, stream>>>(
        qbuf, kvb, vtb, mpk, resb);
    gemm_bt<float><<<dim3(D_MODEL/128, M/128), 256, 0, stream>>>(
        resb, woT, bo, out, D_MODEL, D_MODEL, 1.0f);
}